// Round 3
// baseline (9.791 us; speedup 1.0000x reference)
//
#include <hip/hip_runtime.h>

// Problem constants: B=4, N=64 labels, H=W=512.
#define BB 4
#define NN 64
#define HH 512
#define WW 512
#define RPB 4                       // rows per block -> grid = 4*128 = 512 = 2/CU
#define LOG2E 1.4426950408889634f
#define CUT 18.0f                   // drop label if exp2(c2*dy2) < 2^-18 for all rows

__device__ __forceinline__ float exp2f_fast(float x) { return __builtin_amdgcn_exp2f(x); }

// Tail of the integer-grid gaussian sum past a boundary at signed distance u:
//   T(u) = sum_{k>=1} exp(-(u-0.5+k)^2/(2s^2))
//        = s*sqrt(pi/2)*erfc(u/(s*sqrt2)) - (u/s^2)*exp(-u^2/(2s^2))/24
// (midpoint-rule Euler-Maclaurin correction; residual ~1e-5 relative).
// erfc via Abramowitz-Stegun 7.1.26 (|err| <= 1.5e-7); note exp(-x^2) with
// x = u/(s*sqrt2) equals exp2(c2*u^2), shared with the gaussian itself.
__device__ __forceinline__ float tail_T(float u, float A, float invs2,
                                        float c2, float i24) {
    const float g  = exp2f_fast(c2 * u * u);      // e^{-u^2/(2s^2)} = e^{-x^2}
    const float x  = u * invs2;
    const float ax = fabsf(x);
    const float t  = 1.0f / fmaf(0.3275911f, ax, 1.0f);
    const float poly = t * fmaf(t, fmaf(t, fmaf(t, fmaf(t, 1.061405429f,
                        -1.453152027f), 1.421413741f), -0.284496736f),
                        0.254829592f);
    const float e    = poly * g;
    const float erfc = (x >= 0.0f) ? e : (2.0f - e);
    return fmaf(A, erfc, -i24 * u * g);
}

// Single fused kernel, ONE barrier. Block = (b, 4 rows), 512 threads = one
// x-column each. Wave 0: ballot-compact surviving labels, closed-form
// normalization, write lx + eyw[j][r] tables to LDS. Then all threads run the
// separable accumulation (1 exp + 4 fma per survivor) and store.
__global__ __launch_bounds__(512) void fused_density_kernel(
    const float* __restrict__ labels,   // (B,N,2)
    const float* __restrict__ sigma,    // scalar
    float* __restrict__ out)            // (B,1,H,W)
{
    const int nrb = HH / RPB;                  // 128 row-blocks per batch
    const int b   = blockIdx.x / nrb;
    const int y0  = (blockIdx.x % nrb) * RPB;
    const int t   = threadIdx.x;               // 0..511 = x

    __shared__ float lx_s[NN];
    __shared__ float eyw_s[NN][RPB];
    __shared__ int   cnt_s;

    const float s  = sigma[0];
    const float c2 = -LOG2E / (2.0f * s * s);  // exp(-d2/(2s^2)) = exp2(c2*d2)

    if (t < NN) {                              // wave 0 only (NN==64)
        const float lx = labels[(b * NN + t) * 2 + 0];
        const float ly = labels[(b * NN + t) * 2 + 1];
        const float rad = __builtin_sqrtf(CUT / (-c2));
        // distance from ly to nearest row in [y0, y0+RPB-1]
        const float dlo  = (float)y0 - ly;
        const float dhi  = ly - (float)(y0 + RPB - 1);
        const float dmin = fmaxf(fmaxf(dlo, dhi), 0.0f);
        const bool  keep = dmin < rad;
        const unsigned long long mask = __ballot(keep);
        if (keep) {
            const int idx = __popcll(mask & ((1ULL << t) - 1ULL));
            // closed-form row/col sums
            const float A     = s * 1.2533141373155003f;   // s*sqrt(pi/2)
            const float Bf    = s * 2.5066282746310002f;   // s*sqrt(2pi)
            const float invs2 = 1.0f / (s * 1.4142135623730951f);
            const float i24   = 1.0f / (24.0f * s * s);
            const float Sx = Bf - tail_T(lx + 0.5f, A, invs2, c2, i24)
                                - tail_T((float)(WW - 1) + 0.5f - lx, A, invs2, c2, i24);
            const float Sy = Bf - tail_T(ly + 0.5f, A, invs2, c2, i24)
                                - tail_T((float)(HH - 1) + 0.5f - ly, A, invs2, c2, i24);
            const float w  = 1.0f / (Sx * Sy);
            lx_s[idx] = lx;
#pragma unroll
            for (int r = 0; r < RPB; ++r) {
                const float dy = (float)(y0 + r) - ly;
                eyw_s[idx][r] = exp2f_fast(c2 * dy * dy) * w;
            }
        }
        if (t == 0) cnt_s = (int)__popcll(mask);
    }
    __syncthreads();

    const int   cnt = cnt_s;
    const float xf  = (float)t;
    float acc[RPB];
#pragma unroll
    for (int r = 0; r < RPB; ++r) acc[r] = 0.0f;
    for (int j = 0; j < cnt; ++j) {
        const float dx = xf - lx_s[j];
        const float ex = exp2f_fast(c2 * dx * dx);
#pragma unroll
        for (int r = 0; r < RPB; ++r)
            acc[r] = fmaf(ex, eyw_s[j][r], acc[r]);
    }
#pragma unroll
    for (int r = 0; r < RPB; ++r)
        out[(b * HH + y0 + r) * WW + t] = acc[r];
}

extern "C" void kernel_launch(void* const* d_in, const int* in_sizes, int n_in,
                              void* d_out, int out_size, void* d_ws, size_t ws_size,
                              hipStream_t stream) {
    // d_in[0]: batch_images (unused), d_in[1]: batch_labels (B,N,2), d_in[2]: sigma
    const float* labels = (const float*)d_in[1];
    const float* sigma  = (const float*)d_in[2];
    float*       out    = (float*)d_out;

    fused_density_kernel<<<BB * (HH / RPB), 512, 0, stream>>>(labels, sigma, out);
}